// Round 2
// baseline (9295.423 us; speedup 1.0000x reference)
//
#include <hip/hip_runtime.h>
#include <math.h>

#define SQ 8
#define NN 100000
#define EE 1600000
#define LL 3
#define BB 128
#define HRR 128
#define ROWS 16                        // nodes per wave
#define TILE 64                        // nodes per block (4 waves)
#define NTILE ((NN + TILE - 1) / TILE) // 1563 blocks
#define NBLK ((NN + 255) / 256)        // 391 (scan kernels)

__device__ __forceinline__ float fast_tanh(float x) {
    x = fminf(fmaxf(x, -15.f), 15.f);
    float e = __expf(2.f * x);                      // v_exp path, branchless
    return (e - 1.f) * __builtin_amdgcn_rcpf(e + 1.f);
}

// ---------------- CSR build ----------------

__global__ void k_hist(const int* __restrict__ dst, int* __restrict__ deg) {
    int e = blockIdx.x * blockDim.x + threadIdx.x;
    if (e < EE) atomicAdd(&deg[dst[e]], 1);
}

__global__ void k_scan1(const int* __restrict__ deg, int* __restrict__ excl,
                        int* __restrict__ bsums) {
    __shared__ int buf[256];
    int tid = threadIdx.x;
    int i = blockIdx.x * 256 + tid;
    int v = (i < NN) ? deg[i] : 0;
    buf[tid] = v;
    __syncthreads();
    for (int off = 1; off < 256; off <<= 1) {
        int t = (tid >= off) ? buf[tid - off] : 0;
        __syncthreads();
        buf[tid] += t;
        __syncthreads();
    }
    if (i < NN) excl[i] = buf[tid] - v;
    if (tid == 255) bsums[blockIdx.x] = buf[255];
}

__global__ void k_scan2(const int* __restrict__ bsums, int* __restrict__ boff) {
    __shared__ int buf[512];
    int tid = threadIdx.x;
    int v = (tid < NBLK) ? bsums[tid] : 0;
    buf[tid] = v;
    __syncthreads();
    for (int off = 1; off < 512; off <<= 1) {
        int t = (tid >= off) ? buf[tid - off] : 0;
        __syncthreads();
        buf[tid] += t;
        __syncthreads();
    }
    if (tid < NBLK) boff[tid] = buf[tid] - v;
}

__global__ void k_scan3(int* __restrict__ row_start, const int* __restrict__ boff,
                        int* __restrict__ cursor) {
    int tid = threadIdx.x;
    int i = blockIdx.x * 256 + tid;
    if (i < NN) {
        int r = row_start[i] + boff[blockIdx.x];
        row_start[i] = r;
        cursor[i] = r;
    }
    if (blockIdx.x == 0 && tid == 0) row_start[NN] = EE;
}

__global__ void k_fill(const int* __restrict__ src, const int* __restrict__ dst,
                       int* __restrict__ cursor, int* __restrict__ csr) {
    int e = blockIdx.x * blockDim.x + threadIdx.x;
    if (e < EE) {
        int d = dst[e];
        int p = atomicAdd(&cursor[d], 1);
        csr[p] = src[e];
    }
}

// ---------------- GIN stage 1: agg + MLP1 + BN partial stats ----------------
// wave = 16 nodes, lane = channel; weights held in 64 VGPRs per lane.

__global__ __launch_bounds__(256, 4) void k_agg_mlp1(
    const float* __restrict__ xin, const int* __restrict__ row_start,
    const int* __restrict__ csr, const float* __restrict__ W1,
    const float* __restrict__ b1, float* __restrict__ h_out,
    float* __restrict__ stats) {
    int tid = threadIdx.x;
    int wave = tid >> 6, lane = tid & 63;
    float w[64];
#pragma unroll
    for (int c = 0; c < 64; c++) w[c] = W1[c * 64 + lane];  // coalesced per c
    float bias = b1[lane];
    int base = blockIdx.x * TILE + wave * ROWS;
    float aS = 0.f, aQ = 0.f;
    for (int r = 0; r < ROWS; r++) {
        int i = base + r;
        if (i >= NN) break;
        float s = xin[(size_t)i * 64 + lane];
        int e0 = row_start[i], e1 = row_start[i + 1];
        for (int eb = e0; eb < e1; eb += 64) {
            int m = e1 - eb; if (m > 64) m = 64;
            int id = (lane < m) ? csr[eb + lane] : 0;
            for (int k = 0; k < m; k++) {
                int nb = __shfl(id, k, 64);
                s += xin[(size_t)nb * 64 + lane];
            }
        }
        float h0 = bias, h1 = 0.f;
#pragma unroll
        for (int c = 0; c < 64; c += 2) {
            h0 = fmaf(__shfl(s, c, 64), w[c], h0);
            h1 = fmaf(__shfl(s, c + 1, 64), w[c + 1], h1);
        }
        float h = h0 + h1;
        h_out[(size_t)i * 64 + lane] = h;
        aS += h;
        aQ += h * h;
    }
    __shared__ float sSum[4][64];
    __shared__ float sSq[4][64];
    sSum[wave][lane] = aS;
    sSq[wave][lane] = aQ;
    __syncthreads();
    if (wave == 0) {
        float s4 = sSum[0][lane] + sSum[1][lane] + sSum[2][lane] + sSum[3][lane];
        float q4 = sSq[0][lane] + sSq[1][lane] + sSq[2][lane] + sSq[3][lane];
        atomicAdd(&stats[lane], s4);
        atomicAdd(&stats[64 + lane], q4);
    }
}

// ---------------- GIN stage 2: BN + tanh + MLP2 + tanh (+ pool on last layer) ----------------

__global__ __launch_bounds__(256, 4) void k_bn_mlp2(
    const float* __restrict__ h_in, const float* __restrict__ W2,
    const float* __restrict__ b2, const float* __restrict__ gamma,
    const float* __restrict__ beta, const float* __restrict__ stats,
    float* __restrict__ x_out, float* __restrict__ g_pool,
    const int* __restrict__ batch) {
    int tid = threadIdx.x;
    int wave = tid >> 6, lane = tid & 63;
    float w[64];
#pragma unroll
    for (int c = 0; c < 64; c++) w[c] = W2[c * 64 + lane];
    float bias = b2[lane];
    float mu = stats[lane] * (1.0f / NN);
    float var = stats[64 + lane] * (1.0f / NN) - mu * mu;
    float scale = rsqrtf(var + 1e-5f) * gamma[lane];
    float shift = beta[lane] - mu * scale;
    int base = blockIdx.x * TILE + wave * ROWS;
    float pacc = 0.f;
    int pbid = -1;
    for (int r = 0; r < ROWS; r++) {
        int i = base + r;
        if (i >= NN) break;
        float v = h_in[(size_t)i * 64 + lane];
        float s = fast_tanh(fmaf(v, scale, shift));
        float h0 = bias, h1 = 0.f;
#pragma unroll
        for (int c = 0; c < 64; c += 2) {
            h0 = fmaf(__shfl(s, c, 64), w[c], h0);
            h1 = fmaf(__shfl(s, c + 1, 64), w[c + 1], h1);
        }
        float o = fast_tanh(h0 + h1);
        if (x_out) {
            x_out[(size_t)i * 64 + lane] = o;
        } else {
            int bid = batch[i];  // sorted -> few distinct per wave
            if (bid != pbid) {
                if (pbid >= 0) atomicAdd(&g_pool[pbid * 64 + lane], pacc);
                pacc = 0.f;
                pbid = bid;
            }
            pacc += o;
        }
    }
    if (g_pool && pbid >= 0) atomicAdd(&g_pool[pbid * 64 + lane], pacc);
}

// ---------------- tail ----------------

__global__ void k_pool_proj(const float* __restrict__ g_all, const float* __restrict__ Wg,
                            const float* __restrict__ bg, float* __restrict__ seq) {
    int idx = blockIdx.x * 256 + threadIdx.x;  // S*B*64
    int o = idx & 63, row = idx >> 6;
    float acc = bg[o];
    const float* g = g_all + (size_t)row * 64;
#pragma unroll 8
    for (int c = 0; c < 64; c++) acc = fmaf(g[c], Wg[c * 64 + o], acc);
    seq[idx] = acc;
}

__global__ void k_transpose(const float* __restrict__ in, float* __restrict__ out,
                            int rows, int cols) {
    int idx = blockIdx.x * blockDim.x + threadIdx.x;
    if (idx < rows * cols) {
        int r = idx / cols, c = idx % cols;
        out[c * rows + r] = in[idx];
    }
}

// one block per batch row; loops all 8 timesteps + final sigmoid readout
__global__ __launch_bounds__(128) void k_rnn_all(
    const float* __restrict__ seq, const float* __restrict__ WihT,
    const float* __restrict__ WhhT, const float* __restrict__ bih,
    const float* __restrict__ bhh, const float* __restrict__ Wr,
    const float* __restrict__ br, float* __restrict__ out) {
    int b = blockIdx.x, j = threadIdx.x;
    __shared__ float sh[128];
    __shared__ float sx[64];
    __shared__ float sp[128];
    sh[j] = 0.f;
    float bsum = bih[j] + bhh[j];
    __syncthreads();
    for (int t = 0; t < SQ; t++) {
        if (j < 64) sx[j] = seq[((size_t)t * BB + b) * 64 + j];
        __syncthreads();
        float acc = bsum;
#pragma unroll 16
        for (int c = 0; c < 64; c++) acc = fmaf(sx[c], WihT[c * 128 + j], acc);
#pragma unroll 16
        for (int k = 0; k < 128; k++) acc = fmaf(sh[k], WhhT[k * 128 + j], acc);
        acc = tanhf(acc);
        __syncthreads();
        sh[j] = acc;
        __syncthreads();
    }
    sp[j] = sh[j] * Wr[j];
    __syncthreads();
    if (j == 0) {
        float a = br[0];
        for (int k = 0; k < 128; k++) a += sp[k];
        out[b] = 1.f / (1.f + expf(-a));
    }
}

// ---------------- launch ----------------

extern "C" void kernel_launch(void* const* d_in, const int* in_sizes, int n_in,
                              void* d_out, int out_size, void* d_ws, size_t ws_size,
                              hipStream_t stream) {
    const float* xs    = (const float*)d_in[0];
    const int*   edge  = (const int*)d_in[1];
    const int*   batch = (const int*)d_in[2];
    const float* W1    = (const float*)d_in[3];
    const float* b1    = (const float*)d_in[4];
    const float* gamma = (const float*)d_in[5];
    const float* beta  = (const float*)d_in[6];
    const float* W2    = (const float*)d_in[7];
    const float* b2    = (const float*)d_in[8];
    const float* Wg    = (const float*)d_in[9];
    const float* bg    = (const float*)d_in[10];
    const float* Wih   = (const float*)d_in[11];
    const float* Whh   = (const float*)d_in[12];
    const float* bih   = (const float*)d_in[13];
    const float* bhh   = (const float*)d_in[14];
    const float* Wr    = (const float*)d_in[15];
    const float* br    = (const float*)d_in[16];

    char* p = (char*)d_ws;
    auto alloc = [&](size_t bytes) -> char* {
        char* r = p;
        p += (bytes + 255) & ~(size_t)255;
        return r;
    };
    float* x_cur     = (float*)alloc((size_t)NN * 64 * 4);
    float* h_tmp     = (float*)alloc((size_t)NN * 64 * 4);
    float* g_all     = (float*)alloc((size_t)SQ * BB * 64 * 4);
    float* seq       = (float*)alloc((size_t)SQ * BB * 64 * 4);
    float* WihT      = (float*)alloc((size_t)64 * HRR * 4);
    float* WhhT      = (float*)alloc((size_t)HRR * HRR * 4);
    float* stats     = (float*)alloc((size_t)SQ * LL * 128 * 4);
    int*   row_start = (int*)alloc((size_t)(NN + 1) * 4);
    int*   cursor    = (int*)alloc((size_t)NN * 4);
    int*   deg       = (int*)alloc((size_t)NN * 4);
    int*   csr       = (int*)alloc((size_t)EE * 4);
    int*   bsums     = (int*)alloc(512 * 4);
    int*   boff      = (int*)alloc(512 * 4);

    hipMemsetAsync(stats, 0, (size_t)SQ * LL * 128 * 4, stream);
    hipMemsetAsync(g_all, 0, (size_t)SQ * BB * 64 * 4, stream);
    k_transpose<<<(128 * 64 + 255) / 256, 256, 0, stream>>>(Wih, WihT, 128, 64);
    k_transpose<<<(128 * 128 + 255) / 256, 256, 0, stream>>>(Whh, WhhT, 128, 128);

    int ghist = EE / 256;  // 6250
    for (int t = 0; t < SQ; t++) {
        const int* src = edge + (size_t)t * 2 * EE;
        const int* dst = src + EE;
        hipMemsetAsync(deg, 0, (size_t)NN * 4, stream);
        k_hist<<<ghist, 256, 0, stream>>>(dst, deg);
        k_scan1<<<NBLK, 256, 0, stream>>>(deg, row_start, bsums);
        k_scan2<<<1, 512, 0, stream>>>(bsums, boff);
        k_scan3<<<NBLK, 256, 0, stream>>>(row_start, boff, cursor);
        k_fill<<<ghist, 256, 0, stream>>>(src, dst, cursor, csr);
        for (int l = 0; l < LL; l++) {
            int pl = t * LL + l;
            const float* xin = (l == 0) ? xs + (size_t)t * NN * 64 : x_cur;
            k_agg_mlp1<<<NTILE, 256, 0, stream>>>(xin, row_start, csr,
                                                  W1 + (size_t)pl * 4096, b1 + (size_t)pl * 64,
                                                  h_tmp, stats + (size_t)pl * 128);
            k_bn_mlp2<<<NTILE, 256, 0, stream>>>(h_tmp, W2 + (size_t)pl * 4096,
                                                 b2 + (size_t)pl * 64, gamma + (size_t)pl * 64,
                                                 beta + (size_t)pl * 64, stats + (size_t)pl * 128,
                                                 (l < 2) ? x_cur : nullptr,
                                                 (l == 2) ? (g_all + (size_t)t * BB * 64) : nullptr,
                                                 batch);
        }
    }
    k_pool_proj<<<SQ * BB * 64 / 256, 256, 0, stream>>>(g_all, Wg, bg, seq);
    k_rnn_all<<<BB, 128, 0, stream>>>(seq, WihT, WhhT, bih, bhh, Wr, br, (float*)d_out);
}

// Round 4
// 7726.608 us; speedup vs baseline: 1.2030x; 1.2030x over previous
//
#include <hip/hip_runtime.h>
#include <math.h>

#define SQ 8
#define NN 100000
#define EE 1600000
#define LL 3
#define BB 128
#define HRR 128
#define ROWS 16                        // nodes per wave
#define TILE 64                        // nodes per block (4 waves)
#define NTILE ((NN + TILE - 1) / TILE) // 1563 blocks
#define NBLK ((NN + 255) / 256)        // 391 (scan kernels)

__device__ __forceinline__ float fast_tanh(float x) {
    x = fminf(fmaxf(x, -15.f), 15.f);
    float e = __expf(2.f * x);
    return (e - 1.f) * __builtin_amdgcn_rcpf(e + 1.f);
}

// ---------------- CSR build ----------------

__global__ void k_hist(const int* __restrict__ dst, int* __restrict__ deg) {
    int e = blockIdx.x * blockDim.x + threadIdx.x;
    if (e < EE) atomicAdd(&deg[dst[e]], 1);
}

__global__ void k_scan1(const int* __restrict__ deg, int* __restrict__ excl,
                        int* __restrict__ bsums) {
    __shared__ int buf[256];
    int tid = threadIdx.x;
    int i = blockIdx.x * 256 + tid;
    int v = (i < NN) ? deg[i] : 0;
    buf[tid] = v;
    __syncthreads();
    for (int off = 1; off < 256; off <<= 1) {
        int t = (tid >= off) ? buf[tid - off] : 0;
        __syncthreads();
        buf[tid] += t;
        __syncthreads();
    }
    if (i < NN) excl[i] = buf[tid] - v;
    if (tid == 255) bsums[blockIdx.x] = buf[255];
}

__global__ void k_scan2(const int* __restrict__ bsums, int* __restrict__ boff) {
    __shared__ int buf[512];
    int tid = threadIdx.x;
    int v = (tid < NBLK) ? bsums[tid] : 0;
    buf[tid] = v;
    __syncthreads();
    for (int off = 1; off < 512; off <<= 1) {
        int t = (tid >= off) ? buf[tid - off] : 0;
        __syncthreads();
        buf[tid] += t;
        __syncthreads();
    }
    if (tid < NBLK) boff[tid] = buf[tid] - v;
}

__global__ void k_scan3(int* __restrict__ row_start, const int* __restrict__ boff,
                        int* __restrict__ cursor) {
    int tid = threadIdx.x;
    int i = blockIdx.x * 256 + tid;
    if (i < NN) {
        int r = row_start[i] + boff[blockIdx.x];
        row_start[i] = r;
        cursor[i] = r;
    }
    if (blockIdx.x == 0 && tid == 0) row_start[NN] = EE;
}

__global__ void k_fill(const int* __restrict__ src, const int* __restrict__ dst,
                       int* __restrict__ cursor, int* __restrict__ csr) {
    int e = blockIdx.x * blockDim.x + threadIdx.x;
    if (e < EE) {
        int d = dst[e];
        int p = atomicAdd(&cursor[d], 1);
        csr[p] = src[e];
    }
}

// ---------------- GIN stage 1: agg + MLP1 + BN partial stats ----------------
// wave = 16 nodes, lane = channel; weights in LDS; 8-wide batched gather (MLP).

__global__ __launch_bounds__(256, 6) void k_agg_mlp1(
    const float* __restrict__ xin, const int* __restrict__ row_start,
    const int* __restrict__ csr, const float* __restrict__ W1,
    const float* __restrict__ b1, float* __restrict__ h_out,
    float* __restrict__ stats) {
    __shared__ float sW[4096];
    __shared__ float sSum[4][64];
    __shared__ float sSq[4][64];
    int tid = threadIdx.x;
    for (int k = tid; k < 4096; k += 256) sW[k] = W1[k];
    __syncthreads();
    int wave = tid >> 6, lane = tid & 63;
    float bias = b1[lane];
    int base = blockIdx.x * TILE + wave * ROWS;
    float aS = 0.f, aQ = 0.f;
    for (int r = 0; r < ROWS; r++) {
        int i = base + r;
        if (i >= NN) break;
        float s = xin[(size_t)i * 64 + lane];
        int e0 = row_start[i], e1 = row_start[i + 1];
        int eb = e0;
        while (eb < e1) {
            int m = e1 - eb; if (m > 64) m = 64;
            int id = (lane < m) ? csr[eb + lane] : 0;
            int k = 0;
            for (; k + 8 <= m; k += 8) {
                // 8 independent loads in flight before any dependent add
                const size_t o = lane;
                float v0 = xin[(size_t)__shfl(id, k + 0, 64) * 64 + o];
                float v1 = xin[(size_t)__shfl(id, k + 1, 64) * 64 + o];
                float v2 = xin[(size_t)__shfl(id, k + 2, 64) * 64 + o];
                float v3 = xin[(size_t)__shfl(id, k + 3, 64) * 64 + o];
                float v4 = xin[(size_t)__shfl(id, k + 4, 64) * 64 + o];
                float v5 = xin[(size_t)__shfl(id, k + 5, 64) * 64 + o];
                float v6 = xin[(size_t)__shfl(id, k + 6, 64) * 64 + o];
                float v7 = xin[(size_t)__shfl(id, k + 7, 64) * 64 + o];
                s += ((v0 + v1) + (v2 + v3)) + ((v4 + v5) + (v6 + v7));
            }
            for (; k + 2 <= m; k += 2) {
                float v0 = xin[(size_t)__shfl(id, k + 0, 64) * 64 + lane];
                float v1 = xin[(size_t)__shfl(id, k + 1, 64) * 64 + lane];
                s += v0 + v1;
            }
            for (; k < m; k++) s += xin[(size_t)__shfl(id, k, 64) * 64 + lane];
            eb += m;
        }
        float h0 = bias, h1 = 0.f, h2 = 0.f, h3 = 0.f;
#pragma unroll
        for (int c = 0; c < 64; c += 4) {
            h0 = fmaf(__shfl(s, c + 0, 64), sW[(c + 0) * 64 + lane], h0);
            h1 = fmaf(__shfl(s, c + 1, 64), sW[(c + 1) * 64 + lane], h1);
            h2 = fmaf(__shfl(s, c + 2, 64), sW[(c + 2) * 64 + lane], h2);
            h3 = fmaf(__shfl(s, c + 3, 64), sW[(c + 3) * 64 + lane], h3);
        }
        float h = (h0 + h1) + (h2 + h3);
        h_out[(size_t)i * 64 + lane] = h;
        aS += h;
        aQ += h * h;
    }
    sSum[wave][lane] = aS;
    sSq[wave][lane] = aQ;
    __syncthreads();
    if (wave == 0) {
        float s4 = sSum[0][lane] + sSum[1][lane] + sSum[2][lane] + sSum[3][lane];
        float q4 = sSq[0][lane] + sSq[1][lane] + sSq[2][lane] + sSq[3][lane];
        atomicAdd(&stats[lane], s4);
        atomicAdd(&stats[64 + lane], q4);
    }
}

// ---------------- GIN stage 2: BN + tanh + MLP2 + tanh (+ pool on last layer) ----------------

__global__ __launch_bounds__(256, 6) void k_bn_mlp2(
    const float* __restrict__ h_in, const float* __restrict__ W2,
    const float* __restrict__ b2, const float* __restrict__ gamma,
    const float* __restrict__ beta, const float* __restrict__ stats,
    float* __restrict__ x_out, float* __restrict__ g_pool,
    const int* __restrict__ batch) {
    __shared__ float sW[4096];
    int tid = threadIdx.x;
    for (int k = tid; k < 4096; k += 256) sW[k] = W2[k];
    __syncthreads();
    int wave = tid >> 6, lane = tid & 63;
    float bias = b2[lane];
    float mu = stats[lane] * (1.0f / NN);
    float var = stats[64 + lane] * (1.0f / NN) - mu * mu;
    float scale = rsqrtf(var + 1e-5f) * gamma[lane];
    float shift = beta[lane] - mu * scale;
    int base = blockIdx.x * TILE + wave * ROWS;
    float pacc = 0.f;
    int pbid = -1;
    for (int r = 0; r < ROWS; r++) {
        int i = base + r;
        if (i >= NN) break;
        float v = h_in[(size_t)i * 64 + lane];
        float s = fast_tanh(fmaf(v, scale, shift));
        float h0 = bias, h1 = 0.f, h2 = 0.f, h3 = 0.f;
#pragma unroll
        for (int c = 0; c < 64; c += 4) {
            h0 = fmaf(__shfl(s, c + 0, 64), sW[(c + 0) * 64 + lane], h0);
            h1 = fmaf(__shfl(s, c + 1, 64), sW[(c + 1) * 64 + lane], h1);
            h2 = fmaf(__shfl(s, c + 2, 64), sW[(c + 2) * 64 + lane], h2);
            h3 = fmaf(__shfl(s, c + 3, 64), sW[(c + 3) * 64 + lane], h3);
        }
        float o = fast_tanh((h0 + h1) + (h2 + h3));
        if (x_out) {
            x_out[(size_t)i * 64 + lane] = o;
        } else {
            int bid = batch[i];  // sorted -> few distinct per wave
            if (bid != pbid) {
                if (pbid >= 0) atomicAdd(&g_pool[pbid * 64 + lane], pacc);
                pacc = 0.f;
                pbid = bid;
            }
            pacc += o;
        }
    }
    if (g_pool && pbid >= 0) atomicAdd(&g_pool[pbid * 64 + lane], pacc);
}

// ---------------- tail ----------------

__global__ void k_pool_proj(const float* __restrict__ g_all, const float* __restrict__ Wg,
                            const float* __restrict__ bg, float* __restrict__ seq) {
    int idx = blockIdx.x * 256 + threadIdx.x;  // S*B*64
    int o = idx & 63, row = idx >> 6;
    float acc = bg[o];
    const float* g = g_all + (size_t)row * 64;
#pragma unroll 8
    for (int c = 0; c < 64; c++) acc = fmaf(g[c], Wg[c * 64 + o], acc);
    seq[idx] = acc;
}

__global__ void k_transpose(const float* __restrict__ in, float* __restrict__ out,
                            int rows, int cols) {
    int idx = blockIdx.x * blockDim.x + threadIdx.x;
    if (idx < rows * cols) {
        int r = idx / cols, c = idx % cols;
        out[c * rows + r] = in[idx];
    }
}

// one block per batch row; loops all 8 timesteps + final sigmoid readout
__global__ __launch_bounds__(128) void k_rnn_all(
    const float* __restrict__ seq, const float* __restrict__ WihT,
    const float* __restrict__ WhhT, const float* __restrict__ bih,
    const float* __restrict__ bhh, const float* __restrict__ Wr,
    const float* __restrict__ br, float* __restrict__ out) {
    int b = blockIdx.x, j = threadIdx.x;
    __shared__ float sh[128];
    __shared__ float sx[64];
    __shared__ float sp[128];
    sh[j] = 0.f;
    float bsum = bih[j] + bhh[j];
    __syncthreads();
    for (int t = 0; t < SQ; t++) {
        if (j < 64) sx[j] = seq[((size_t)t * BB + b) * 64 + j];
        __syncthreads();
        float acc = bsum;
#pragma unroll 16
        for (int c = 0; c < 64; c++) acc = fmaf(sx[c], WihT[c * 128 + j], acc);
#pragma unroll 16
        for (int k = 0; k < 128; k++) acc = fmaf(sh[k], WhhT[k * 128 + j], acc);
        acc = tanhf(acc);
        __syncthreads();
        sh[j] = acc;
        __syncthreads();
    }
    sp[j] = sh[j] * Wr[j];
    __syncthreads();
    if (j == 0) {
        float a = br[0];
        for (int k = 0; k < 128; k++) a += sp[k];
        out[b] = 1.f / (1.f + expf(-a));
    }
}

// ---------------- launch ----------------

extern "C" void kernel_launch(void* const* d_in, const int* in_sizes, int n_in,
                              void* d_out, int out_size, void* d_ws, size_t ws_size,
                              hipStream_t stream) {
    const float* xs    = (const float*)d_in[0];
    const int*   edge  = (const int*)d_in[1];
    const int*   batch = (const int*)d_in[2];
    const float* W1    = (const float*)d_in[3];
    const float* b1    = (const float*)d_in[4];
    const float* gamma = (const float*)d_in[5];
    const float* beta  = (const float*)d_in[6];
    const float* W2    = (const float*)d_in[7];
    const float* b2    = (const float*)d_in[8];
    const float* Wg    = (const float*)d_in[9];
    const float* bg    = (const float*)d_in[10];
    const float* Wih   = (const float*)d_in[11];
    const float* Whh   = (const float*)d_in[12];
    const float* bih   = (const float*)d_in[13];
    const float* bhh   = (const float*)d_in[14];
    const float* Wr    = (const float*)d_in[15];
    const float* br    = (const float*)d_in[16];

    char* p = (char*)d_ws;
    auto alloc = [&](size_t bytes) -> char* {
        char* r = p;
        p += (bytes + 255) & ~(size_t)255;
        return r;
    };
    float* x_cur     = (float*)alloc((size_t)NN * 64 * 4);
    float* h_tmp     = (float*)alloc((size_t)NN * 64 * 4);
    float* g_all     = (float*)alloc((size_t)SQ * BB * 64 * 4);
    float* seq       = (float*)alloc((size_t)SQ * BB * 64 * 4);
    float* WihT      = (float*)alloc((size_t)64 * HRR * 4);
    float* WhhT      = (float*)alloc((size_t)HRR * HRR * 4);
    float* stats     = (float*)alloc((size_t)SQ * LL * 128 * 4);
    int*   row_start = (int*)alloc((size_t)(NN + 1) * 4);
    int*   cursor    = (int*)alloc((size_t)NN * 4);
    int*   deg       = (int*)alloc((size_t)NN * 4);
    int*   csr       = (int*)alloc((size_t)EE * 4);
    int*   bsums     = (int*)alloc(512 * 4);
    int*   boff      = (int*)alloc(512 * 4);

    hipMemsetAsync(stats, 0, (size_t)SQ * LL * 128 * 4, stream);
    hipMemsetAsync(g_all, 0, (size_t)SQ * BB * 64 * 4, stream);
    k_transpose<<<(128 * 64 + 255) / 256, 256, 0, stream>>>(Wih, WihT, 128, 64);
    k_transpose<<<(128 * 128 + 255) / 256, 256, 0, stream>>>(Whh, WhhT, 128, 128);

    int ghist = EE / 256;  // 6250
    for (int t = 0; t < SQ; t++) {
        const int* src = edge + (size_t)t * 2 * EE;
        const int* dst = src + EE;
        hipMemsetAsync(deg, 0, (size_t)NN * 4, stream);
        k_hist<<<ghist, 256, 0, stream>>>(dst, deg);
        k_scan1<<<NBLK, 256, 0, stream>>>(deg, row_start, bsums);
        k_scan2<<<1, 512, 0, stream>>>(bsums, boff);
        k_scan3<<<NBLK, 256, 0, stream>>>(row_start, boff, cursor);
        k_fill<<<ghist, 256, 0, stream>>>(src, dst, cursor, csr);
        for (int l = 0; l < LL; l++) {
            int pl = t * LL + l;
            const float* xin = (l == 0) ? xs + (size_t)t * NN * 64 : x_cur;
            k_agg_mlp1<<<NTILE, 256, 0, stream>>>(xin, row_start, csr,
                                                  W1 + (size_t)pl * 4096, b1 + (size_t)pl * 64,
                                                  h_tmp, stats + (size_t)pl * 128);
            k_bn_mlp2<<<NTILE, 256, 0, stream>>>(h_tmp, W2 + (size_t)pl * 4096,
                                                 b2 + (size_t)pl * 64, gamma + (size_t)pl * 64,
                                                 beta + (size_t)pl * 64, stats + (size_t)pl * 128,
                                                 (l < 2) ? x_cur : nullptr,
                                                 (l == 2) ? (g_all + (size_t)t * BB * 64) : nullptr,
                                                 batch);
        }
    }
    k_pool_proj<<<SQ * BB * 64 / 256, 256, 0, stream>>>(g_all, Wg, bg, seq);
    k_rnn_all<<<BB, 128, 0, stream>>>(seq, WihT, WhhT, bih, bhh, Wr, br, (float*)d_out);
}